// Round 10
// baseline (204.626 us; speedup 1.0000x reference)
//
#include <hip/hip_runtime.h>

#define N_NODES 50000
#define N_EDGES 800000

// ws layout (in floats):
//  [0, 400000)          esr[node][8] (fallback path only)
//  [400000, 404096)     consts[k][32]   (consts[26] = c_node bias)
//  [404608, 412800)     cnts[26][196] ints (side*13+bucket major)
//  [412800, 10849408)   regions[26][196][512] float4 tuples
//  [10849408, ...)      part_s[10][node][4] then part_r[10][node][4]
#define ESR_OFF    0
#define CONSTS_OFF 400000
#define CNTS_OFF   404608
#define REG_OFF    412800
#define PART_OFF   10849408

#define NBKT    13       // bucket = node >> 12 (4096 nodes per bucket)
#define BKSZ    4096
#define CAP     512      // slots per (block,side,bucket); mean 335, +10 sigma
#define PB      196      // partition blocks (196*1024*4 = 802816 >= E)
#define NCH     10       // reduce chunks; grid 26*10 = 260 blocks
#define BT      1024

// Front: per-block scalar consts -> consts GEMVs (blocks 0..25) -> edge
// decode -> single-touch PARTITION of edges into (node,e0,e1,e2) tuples
// bucketed by node>>12, per-block regions (no prefix sum; fixed capacity).
// Replaces the 14-pass predicated scan whose issued LDS-atomic slot count
// (~10M, conserved across R5-R9's occupancy/pipeline/pass-count/XCD
// variants) was the invariant ~50 us.
__global__ __launch_bounds__(BT) void front_kernel(
    const float* __restrict__ edges,     // [E][3]
    const float* __restrict__ g,         // [8]
    const int*   __restrict__ senders,   // [E]
    const int*   __restrict__ receivers, // [E]
    const float* __restrict__ W_en, const float* __restrict__ b_en,
    const float* __restrict__ W_ee, const float* __restrict__ b_ee,
    const float* __restrict__ W1,   const float* __restrict__ b1,
    const float* __restrict__ W2,   const float* __restrict__ b2,
    const float* __restrict__ W_dn, const float* __restrict__ b_dn,
    const float* __restrict__ W_de, const float* __restrict__ b_de,
    float* __restrict__ ws,
    float* __restrict__ out_edges,       // [E]
    int do_part)
{
    __shared__ float red[BT];
    __shared__ int   cur[26];
    const int tid  = threadIdx.x;
    const int bid  = blockIdx.x;
    const int nblk = gridDim.x;

    // ---- per-block scalar constants ----
    if (tid < 512) {
        float v = 0.f;
        if (tid < 128)      v = b2[tid] * W_dn[tid];                    // -> c_node
        else if (tid < 256) v = b_ee[tid - 128] * W_de[tid - 128];      // -> cb
        else if (tid < 384) v = W_ee[tid - 256] * W_de[tid - 256];      // -> w0
        else                v = W_ee[128 + tid - 384] * W_de[tid - 384];// -> w1
        red[tid] = v;
    }
    __syncthreads();
    for (int w = 64; w > 0; w >>= 1) {
        if (tid < 512 && (tid & 127) < w) red[tid] += red[tid + w];
        __syncthreads();
    }
    const float c_node = red[0]   + b_dn[0];
    const float cb     = red[128] + b_de[0];
    const float w0     = red[256];
    const float w1     = red[384];
    __syncthreads();
    if (tid < 128) red[tid] = W_ee[256 + tid] * W_de[tid];
    __syncthreads();
    for (int w = 64; w > 0; w >>= 1) {
        if (tid < w) red[tid] += red[tid + w];
        __syncthreads();
    }
    const float w2 = red[0];
    __syncthreads();

    // ---- consts GEMV jobs: consts[k][s], s in [0,26) (blocks 0..25) ----
    const int k  = tid & 127;
    const int lh = tid >> 7;     // 0..7, wave-uniform
    float* consts = ws + CONSTS_OFF;
    for (int s = bid; s < 26; s += nblk) {
        if (s < 25) {
            const float* lhs; int off;
            if (s < 16)      { lhs = W_en + s * 128;        off = 0;   }
            else if (s < 19) { lhs = W_ee + (s - 16) * 128; off = 128; }
            else if (s < 22) { lhs = W_ee + (s - 19) * 128; off = 256; }
            else if (s == 22){ lhs = b_en;                  off = 0;   }
            else if (s == 23){ lhs = b_ee;                  off = 128; }
            else             { lhs = b_ee;                  off = 256; }
            float a = 0.f;
            const int l0 = lh * 16;
#pragma unroll
            for (int u = 0; u < 16; ++u)
                a += lhs[l0 + u] * W1[(off + l0 + u) * 128 + k];
            __syncthreads();
            red[tid] = a;
            __syncthreads();
            if (lh == 0) {
                float val = red[k] + red[k + 128] + red[k + 256] + red[k + 384]
                          + red[k + 512] + red[k + 640] + red[k + 768] + red[k + 896];
                if (s == 22) {
                    val += b1[k];
#pragma unroll
                    for (int j = 0; j < 8; ++j)
                        val += g[j] * W1[(384 + j) * 128 + k];
                }
                consts[k * 32 + s] = val;
            }
        } else {  // s == 25: consts[k][25] = W2[k][:] . W_dn; also c_node
            float a = 0.f;
            const int j0 = lh * 16;
#pragma unroll
            for (int u = 0; u < 16; ++u)
                a += W2[k * 128 + j0 + u] * W_dn[j0 + u];
            __syncthreads();
            red[tid] = a;
            __syncthreads();
            if (lh == 0) {
                consts[k * 32 + 25] = red[k] + red[k + 128] + red[k + 256] + red[k + 384]
                                    + red[k + 512] + red[k + 640] + red[k + 768] + red[k + 896];
                consts[k * 32 + 26] = c_node;   // node bias, read as cst[26]
                consts[k * 32 + 27] = 0.f;
            }
        }
    }

    // ---- edge decoder output, grid-stride ----
    for (int q = bid * BT + tid; q < N_EDGES / 4; q += nblk * BT) {
        const int e4 = q * 4;
        const float4* ep = (const float4*)(edges + (size_t)e4 * 3);
        const float4 f0 = ep[0], f1 = ep[1], f2 = ep[2];
        float4 o;
        o.x = fmaf(f0.x, w0, fmaf(f0.y, w1, fmaf(f0.z, w2, cb)));
        o.y = fmaf(f0.w, w0, fmaf(f1.x, w1, fmaf(f1.y, w2, cb)));
        o.z = fmaf(f1.z, w0, fmaf(f1.w, w1, fmaf(f2.x, w2, cb)));
        o.w = fmaf(f2.y, w0, fmaf(f2.z, w1, fmaf(f2.w, w2, cb)));
        *(float4*)(out_edges + e4) = o;
    }

    if (!do_part) return;   // fallback path does aggregation elsewhere

    // ---- single-touch partition: 4 edges/thread ----
    if (tid < 26) cur[tid] = 0;
    __syncthreads();

    const int e4 = (bid * BT + tid) * 4;
    if (e4 < N_EDGES) {
        const int4 sa = *(const int4*)(senders + e4);
        const int4 ra = *(const int4*)(receivers + e4);
        const float4* ep = (const float4*)(edges + (size_t)e4 * 3);
        const float4 f0 = ep[0], f1 = ep[1], f2 = ep[2];
        float4* regs = (float4*)(ws + REG_OFF);

#define PUT(side, node, a, b, c) do {                                       \
            const int bkt_ = (node) >> 12;                                  \
            const int slot_ = atomicAdd(&cur[(side) * NBKT + bkt_], 1);    \
            if (slot_ < CAP) {                                              \
                regs[((size_t)((side) * NBKT + bkt_) * PB + bid) * CAP + slot_] = \
                    make_float4(__int_as_float(node), (a), (b), (c));       \
            }                                                               \
        } while (0)

        PUT(0, sa.x, f0.x, f0.y, f0.z);
        PUT(0, sa.y, f0.w, f1.x, f1.y);
        PUT(0, sa.z, f1.z, f1.w, f2.x);
        PUT(0, sa.w, f2.y, f2.z, f2.w);
        PUT(1, ra.x, f0.x, f0.y, f0.z);
        PUT(1, ra.y, f0.w, f1.x, f1.y);
        PUT(1, ra.z, f1.z, f1.w, f2.x);
        PUT(1, ra.w, f2.y, f2.z, f2.w);
#undef PUT
    }
    __syncthreads();
    if (tid < 26)
        ((int*)(ws + CNTS_OFF))[tid * PB + bid] = min(cur[tid], CAP);
}

// Dense aggregation: block (side,bucket,chunk) streams its share of the
// per-block regions coalesced and applies fully-dense LDS atomics into a
// 64 KB accumulator, then writes the chunk partial.
__global__ __launch_bounds__(BT) void reduce_kernel(
    const float* __restrict__ ws_r,   // regions + cnts (read)
    float* __restrict__ part)         // [2][NCH][N_NODES][4]
{
    __shared__ float4 acc4[BKSZ];     // 65536 B
    float* acc = (float*)acc4;
    const int tid = threadIdx.x;
    const int b26 = blockIdx.x % 26;  // side*13 + bucket
    const int c   = blockIdx.x / 26;  // chunk 0..NCH-1
    const int lo  = (b26 % NBKT) * BKSZ;

    for (int i = tid; i < BKSZ; i += BT)
        acc4[i] = make_float4(0.f, 0.f, 0.f, 0.f);
    __syncthreads();

    const int*    cnts = (const int*)(ws_r + CNTS_OFF) + b26 * PB;
    const float4* regs = (const float4*)(ws_r + REG_OFF);
    const int wave = tid >> 6;
    const int lane = tid & 63;

    // block's region list: blk = c, c+NCH, ...; wave w takes r = w, w+16, ...
    for (int r = wave; ; r += 16) {
        const int blk = c + r * NCH;
        if (blk >= PB) break;
        const int n = cnts[blk];
        const float4* src = regs + ((size_t)b26 * PB + blk) * CAP;
        for (int t = lane; t < n; t += 64) {
            const float4 tp = src[t];
            const int d = __float_as_int(tp.x) - lo;
            float* a = acc + d * 4;
            atomicAdd(a + 0, tp.y);
            atomicAdd(a + 1, tp.z);
            atomicAdd(a + 2, tp.w);
            atomicAdd(a + 3, 1.0f);
        }
    }
    __syncthreads();

    const int hi = min(BKSZ, N_NODES - lo);
    const int side = b26 / NBKT;
    float4* dst = (float4*)(part + ((size_t)side * NCH + c) * (N_NODES * 4)
                                 + (size_t)lo * 4);
    for (int i = tid; i < hi; i += BT)
        dst[i] = acc4[i];
}

// ---- fallback path (tiny ws): global-atomic scatter into esr[node][8] ----
__global__ __launch_bounds__(256) void edge_kernel_atomic(
    const float* __restrict__ edges,
    const int*   __restrict__ senders,
    const int*   __restrict__ receivers,
    float* __restrict__ ws)
{
    const int e = blockIdx.x * 256 + threadIdx.x;
    if (e >= N_EDGES) return;
    const float e0 = edges[e * 3 + 0];
    const float e1 = edges[e * 3 + 1];
    const float e2 = edges[e * 3 + 2];
    const int s = senders[e];
    const int r = receivers[e];
    float* esr = ws + ESR_OFF;
    atomicAdd(&esr[s * 8 + 0], e0);
    atomicAdd(&esr[s * 8 + 1], e1);
    atomicAdd(&esr[s * 8 + 2], e2);
    atomicAdd(&esr[s * 8 + 3], 1.0f);
    atomicAdd(&esr[r * 8 + 4], e0);
    atomicAdd(&esr[r * 8 + 5], e1);
    atomicAdd(&esr[r * 8 + 6], e2);
    atomicAdd(&esr[r * 8 + 7], 1.0f);
}

// Node MLP, latency-split: 256 threads / 128 nodes per block (R6-proven).
__global__ __launch_bounds__(256) void node_kernel(
    const float* __restrict__ nodes,  // [N][16]
    const float* __restrict__ ws,
    const float* __restrict__ part_s,
    const float* __restrict__ part_r,
    float* __restrict__ out_nodes,    // d_out
    int nchunks)
{
    __shared__ float sh[2][128][8];
    __shared__ float red2[256];
    const int tid  = threadIdx.x;
    const int half = tid >> 7;          // 0/1, wave-uniform
    const int ln   = tid & 127;
    const int n    = blockIdx.x * 128 + ln;
    const bool valid = n < N_NODES;

    float4 n0 = make_float4(0,0,0,0), n1 = n0, n2 = n0, n3 = n0;
    if (valid) {
        const float4* np4 = (const float4*)(nodes + (size_t)n * 16);
        n0 = np4[0]; n1 = np4[1]; n2 = np4[2]; n3 = np4[3];
    }

    float4 es = make_float4(0.f, 0.f, 0.f, 0.f);
    float4 er = make_float4(0.f, 0.f, 0.f, 0.f);
    if (valid) {
        if (nchunks > 0) {
            for (int c = half; c < nchunks; c += 2) {
                const float4 a = *(const float4*)(part_s + (size_t)c * (N_NODES * 4) + (size_t)n * 4);
                const float4 b = *(const float4*)(part_r + (size_t)c * (N_NODES * 4) + (size_t)n * 4);
                es.x += a.x; es.y += a.y; es.z += a.z; es.w += a.w;
                er.x += b.x; er.y += b.y; er.z += b.z; er.w += b.w;
            }
        } else if (half == 0) {
            const float4* p = (const float4*)(ws + ESR_OFF + (size_t)n * 8);
            es = p[0];
            er = p[1];
        }
    }
    sh[half][ln][0] = es.x; sh[half][ln][1] = es.y;
    sh[half][ln][2] = es.z; sh[half][ln][3] = es.w;
    sh[half][ln][4] = er.x; sh[half][ln][5] = er.y;
    sh[half][ln][6] = er.z; sh[half][ln][7] = er.w;
    __syncthreads();
    es.x = sh[0][ln][0] + sh[1][ln][0];
    es.y = sh[0][ln][1] + sh[1][ln][1];
    es.z = sh[0][ln][2] + sh[1][ln][2];
    es.w = sh[0][ln][3] + sh[1][ln][3];
    er.x = sh[0][ln][4] + sh[1][ln][4];
    er.y = sh[0][ln][5] + sh[1][ln][5];
    er.z = sh[0][ln][6] + sh[1][ln][6];
    er.w = sh[0][ln][7] + sh[1][ln][7];

    const float* cst = ws + CONSTS_OFF + half * 64 * 32;  // this half's k-range
    float acc = 0.f;
#pragma unroll 4
    for (int kk = 0; kk < 64; ++kk) {
        const float4 m0 = *(const float4*)(cst + kk * 32 + 0);
        const float4 m1 = *(const float4*)(cst + kk * 32 + 4);
        const float4 m2 = *(const float4*)(cst + kk * 32 + 8);
        const float4 m3 = *(const float4*)(cst + kk * 32 + 12);
        const float4 q0 = *(const float4*)(cst + kk * 32 + 16);
        const float4 q1 = *(const float4*)(cst + kk * 32 + 20);
        const float4 q2 = *(const float4*)(cst + kk * 32 + 24);
        float pre = q1.z
            + n0.x * m0.x + n0.y * m0.y + n0.z * m0.z + n0.w * m0.w
            + n1.x * m1.x + n1.y * m1.y + n1.z * m1.z + n1.w * m1.w
            + n2.x * m2.x + n2.y * m2.y + n2.z * m2.z + n2.w * m2.w
            + n3.x * m3.x + n3.y * m3.y + n3.z * m3.z + n3.w * m3.w
            + es.x * q0.x + es.y * q0.y + es.z * q0.z
            + er.x * q0.w + er.y * q1.x + er.z * q1.y
            + es.w * q1.w + er.w * q2.x;
        acc += fmaxf(pre, 0.f) * q2.y;
    }
    red2[tid] = acc;
    __syncthreads();
    if (half == 0 && valid)
        out_nodes[n] = acc + red2[tid + 128] + (ws + CONSTS_OFF)[26];
}

extern "C" void kernel_launch(void* const* d_in, const int* in_sizes, int n_in,
                              void* d_out, int out_size, void* d_ws, size_t ws_size,
                              hipStream_t stream) {
    const float* nodes     = (const float*)d_in[0];
    const float* edges     = (const float*)d_in[1];
    const float* globals_  = (const float*)d_in[2];
    const int*   senders   = (const int*)d_in[3];
    const int*   receivers = (const int*)d_in[4];
    const float* W_en = (const float*)d_in[5];
    const float* b_en = (const float*)d_in[6];
    const float* W_ee = (const float*)d_in[7];
    const float* b_ee = (const float*)d_in[8];
    const float* W1   = (const float*)d_in[9];
    const float* b1   = (const float*)d_in[10];
    const float* W2   = (const float*)d_in[11];
    const float* b2   = (const float*)d_in[12];
    const float* W_dn = (const float*)d_in[13];
    const float* b_dn = (const float*)d_in[14];
    const float* W_de = (const float*)d_in[15];
    const float* b_de = (const float*)d_in[16];

    float* ws  = (float*)d_ws;
    float* out = (float*)d_out;
    float* out_edges = out + N_NODES;

    const long need = (long)PART_OFF + 2L * NCH * N_NODES * 4;
    const long ws_floats = (long)(ws_size / 4);
    const int do_part = (ws_floats >= need) ? 1 : 0;
    const int nch = do_part ? NCH : 0;

    float* part   = ws + PART_OFF;
    float* part_s = part;
    float* part_r = part + (size_t)NCH * (N_NODES * 4);

    front_kernel<<<PB, BT, 0, stream>>>(
        edges, globals_, senders, receivers,
        W_en, b_en, W_ee, b_ee, W1, b1, W2, b2,
        W_dn, b_dn, W_de, b_de, ws, out_edges, do_part);

    if (do_part) {
        reduce_kernel<<<26 * NCH, BT, 0, stream>>>(ws, part);
    } else {
        hipMemsetAsync(ws + ESR_OFF, 0, (size_t)N_NODES * 8 * sizeof(float), stream);
        edge_kernel_atomic<<<(N_EDGES + 255) / 256, 256, 0, stream>>>(
            edges, senders, receivers, ws);
    }

    node_kernel<<<(N_NODES + 127) / 128, 256, 0, stream>>>(
        nodes, ws, part_s, part_r, out, nch);
}

// Round 11
// 175.525 us; speedup vs baseline: 1.1658x; 1.1658x over previous
//
#include <hip/hip_runtime.h>

#define N_NODES 50000
#define N_EDGES 800000

// ws layout (in floats):
//  [0, 400000)        esr[node][8] (fallback path only)
//  [400000, 404096)   consts[k][32]   (consts[26] = c_node bias)
//  [404608, ...)      part_s[c][node][4] then part_r[c][node][4]
#define ESR_OFF    0
#define CONSTS_OFF 400000
#define PART_OFF   404608

#define NBINS   13
#define BINSZ   4096     // 13*4096 = 53248 >= 50000; LDS 65536 B -> 2 blocks/CU
#define MAXCH   19       // 26*19 = 494 blocks, ~2 blocks/CU
#define BT      1024     // 16 waves/block (R6 config)

// Fused front kernel. R11 change vs R6 (the ONLY change): LDS accumulator is
// SoA float[4][BINSZ] instead of AoS [BINSZ][4].
// AoS bank index = (d*4+f)%32 = 4*(d%8)+f -> every ds_add_f32 wave-instruction
// hits only 8 of 32 banks => guaranteed >=8-way serialization on EVERY atomic,
// in EVERY variant R0-R10 (LDS atomics are invisible to SQ_LDS_BANK_CONFLICT).
// SoA bank index = (f*4096+d)%32 = d%32 -> all 32 banks, ~2 lanes/bank (free).
__global__ __launch_bounds__(BT) void front_kernel(
    const float* __restrict__ edges,     // [E][3]
    const float* __restrict__ g,         // [8]
    const int*   __restrict__ senders,   // [E]
    const int*   __restrict__ receivers, // [E]
    const float* __restrict__ W_en, const float* __restrict__ b_en,
    const float* __restrict__ W_ee, const float* __restrict__ b_ee,
    const float* __restrict__ W1,   const float* __restrict__ b1,
    const float* __restrict__ W2,   const float* __restrict__ b2,
    const float* __restrict__ W_dn, const float* __restrict__ b_dn,
    const float* __restrict__ W_de, const float* __restrict__ b_de,
    float* __restrict__ ws,
    float* __restrict__ out_edges,       // [E]
    int nch, int ce)
{
    __shared__ float accp[4 * BINSZ];       // 65536 B; first 4 KB reused as red[]
    float* red  = accp;
    float* acc0 = accp;
    float* acc1 = accp + BINSZ;
    float* acc2 = accp + 2 * BINSZ;
    float* acc3 = accp + 3 * BINSZ;
    const int tid  = threadIdx.x;
    const int bid  = blockIdx.x;
    const int nblk = gridDim.x;

    // ---- per-block scalar constants ----
    if (tid < 512) {
        float v = 0.f;
        if (tid < 128)      v = b2[tid] * W_dn[tid];                    // -> c_node
        else if (tid < 256) v = b_ee[tid - 128] * W_de[tid - 128];      // -> cb
        else if (tid < 384) v = W_ee[tid - 256] * W_de[tid - 256];      // -> w0
        else                v = W_ee[128 + tid - 384] * W_de[tid - 384];// -> w1
        red[tid] = v;
    }
    __syncthreads();
    for (int w = 64; w > 0; w >>= 1) {
        if (tid < 512 && (tid & 127) < w) red[tid] += red[tid + w];
        __syncthreads();
    }
    const float c_node = red[0]   + b_dn[0];
    const float cb     = red[128] + b_de[0];
    const float w0     = red[256];
    const float w1     = red[384];
    __syncthreads();
    if (tid < 128) red[tid] = W_ee[256 + tid] * W_de[tid];
    __syncthreads();
    for (int w = 64; w > 0; w >>= 1) {
        if (tid < w) red[tid] += red[tid + w];
        __syncthreads();
    }
    const float w2 = red[0];
    __syncthreads();

    // ---- consts GEMV jobs: consts[k][s], s in [0,26) (blocks 0..25) ----
    const int k  = tid & 127;
    const int lh = tid >> 7;     // 0..7, wave-uniform
    float* consts = ws + CONSTS_OFF;
    for (int s = bid; s < 26; s += nblk) {
        if (s < 25) {
            const float* lhs; int off;
            if (s < 16)      { lhs = W_en + s * 128;        off = 0;   }
            else if (s < 19) { lhs = W_ee + (s - 16) * 128; off = 128; }
            else if (s < 22) { lhs = W_ee + (s - 19) * 128; off = 256; }
            else if (s == 22){ lhs = b_en;                  off = 0;   }
            else if (s == 23){ lhs = b_ee;                  off = 128; }
            else             { lhs = b_ee;                  off = 256; }
            float a = 0.f;
            const int l0 = lh * 16;
#pragma unroll
            for (int u = 0; u < 16; ++u)
                a += lhs[l0 + u] * W1[(off + l0 + u) * 128 + k];
            __syncthreads();
            red[tid] = a;
            __syncthreads();
            if (lh == 0) {
                float val = red[k] + red[k + 128] + red[k + 256] + red[k + 384]
                          + red[k + 512] + red[k + 640] + red[k + 768] + red[k + 896];
                if (s == 22) {
                    val += b1[k];
#pragma unroll
                    for (int j = 0; j < 8; ++j)
                        val += g[j] * W1[(384 + j) * 128 + k];
                }
                consts[k * 32 + s] = val;
            }
        } else {  // s == 25: consts[k][25] = W2[k][:] . W_dn; also c_node
            float a = 0.f;
            const int j0 = lh * 16;
#pragma unroll
            for (int u = 0; u < 16; ++u)
                a += W2[k * 128 + j0 + u] * W_dn[j0 + u];
            __syncthreads();
            red[tid] = a;
            __syncthreads();
            if (lh == 0) {
                consts[k * 32 + 25] = red[k] + red[k + 128] + red[k + 256] + red[k + 384]
                                    + red[k + 512] + red[k + 640] + red[k + 768] + red[k + 896];
                consts[k * 32 + 26] = c_node;   // node bias, read as cst[26]
                consts[k * 32 + 27] = 0.f;
            }
        }
    }

    // ---- edge decoder output, grid-stride ----
    for (int q = bid * BT + tid; q < N_EDGES / 4; q += nblk * BT) {
        const int e4 = q * 4;
        const float4* ep = (const float4*)(edges + (size_t)e4 * 3);
        const float4 f0 = ep[0], f1 = ep[1], f2 = ep[2];
        float4 o;
        o.x = fmaf(f0.x, w0, fmaf(f0.y, w1, fmaf(f0.z, w2, cb)));
        o.y = fmaf(f0.w, w0, fmaf(f1.x, w1, fmaf(f1.y, w2, cb)));
        o.z = fmaf(f1.z, w0, fmaf(f1.w, w1, fmaf(f2.x, w2, cb)));
        o.w = fmaf(f2.y, w0, fmaf(f2.z, w1, fmaf(f2.w, w2, cb)));
        *(float4*)(out_edges + e4) = o;
    }

    if (nch <= 0) return;   // fallback path does aggregation elsewhere

    // ---- zero LDS accumulator ----
    __syncthreads();
    for (int i = tid; i < 4 * BINSZ; i += BT)
        accp[i] = 0.f;
    __syncthreads();

    // ---- binned aggregation (R6-proven loop; SoA accumulator planes) ----
    const int chunk = bid / 26;
    const int binid = bid % 26;
    const bool is_s = binid < NBINS;
    const int bin   = is_s ? binid : binid - NBINS;
    const int lo    = bin * BINSZ;
    const int* __restrict__ idx = is_s ? senders : receivers;

    const int e_beg = chunk * ce;
    const int e_end = min(e_beg + ce, N_EDGES);
    const int STRIDE = BT * 8;

    int e8 = e_beg + tid * 8;
    int4 ia = make_int4(-1, -1, -1, -1), ib = ia;
    if (e8 < e_end) {
        ia = *(const int4*)(idx + e8);
        ib = *(const int4*)(idx + e8 + 4);
    }
    while (e8 < e_end) {
        const int e8n = e8 + STRIDE;
        int4 ian = ia, ibn = ib;
        if (e8n < e_end) {                    // prefetch next iteration's indices
            ian = *(const int4*)(idx + e8n);
            ibn = *(const int4*)(idx + e8n + 4);
        }
        const unsigned d0 = (unsigned)(ia.x - lo), d1 = (unsigned)(ia.y - lo);
        const unsigned d2 = (unsigned)(ia.z - lo), d3 = (unsigned)(ia.w - lo);
        const unsigned d4 = (unsigned)(ib.x - lo), d5 = (unsigned)(ib.y - lo);
        const unsigned d6 = (unsigned)(ib.z - lo), d7 = (unsigned)(ib.w - lo);
        if ((d0 < BINSZ) | (d1 < BINSZ) | (d2 < BINSZ) | (d3 < BINSZ)) {
            const float4* ep = (const float4*)(edges + (size_t)e8 * 3);
            const float4 f0 = ep[0], f1 = ep[1], f2 = ep[2];
            if (d0 < BINSZ) {
                atomicAdd(&acc0[d0], f0.x); atomicAdd(&acc1[d0], f0.y);
                atomicAdd(&acc2[d0], f0.z); atomicAdd(&acc3[d0], 1.0f);
            }
            if (d1 < BINSZ) {
                atomicAdd(&acc0[d1], f0.w); atomicAdd(&acc1[d1], f1.x);
                atomicAdd(&acc2[d1], f1.y); atomicAdd(&acc3[d1], 1.0f);
            }
            if (d2 < BINSZ) {
                atomicAdd(&acc0[d2], f1.z); atomicAdd(&acc1[d2], f1.w);
                atomicAdd(&acc2[d2], f2.x); atomicAdd(&acc3[d2], 1.0f);
            }
            if (d3 < BINSZ) {
                atomicAdd(&acc0[d3], f2.y); atomicAdd(&acc1[d3], f2.z);
                atomicAdd(&acc2[d3], f2.w); atomicAdd(&acc3[d3], 1.0f);
            }
        }
        if ((d4 < BINSZ) | (d5 < BINSZ) | (d6 < BINSZ) | (d7 < BINSZ)) {
            const float4* ep = (const float4*)(edges + (size_t)e8 * 3 + 12);
            const float4 f0 = ep[0], f1 = ep[1], f2 = ep[2];
            if (d4 < BINSZ) {
                atomicAdd(&acc0[d4], f0.x); atomicAdd(&acc1[d4], f0.y);
                atomicAdd(&acc2[d4], f0.z); atomicAdd(&acc3[d4], 1.0f);
            }
            if (d5 < BINSZ) {
                atomicAdd(&acc0[d5], f0.w); atomicAdd(&acc1[d5], f1.x);
                atomicAdd(&acc2[d5], f1.y); atomicAdd(&acc3[d5], 1.0f);
            }
            if (d6 < BINSZ) {
                atomicAdd(&acc0[d6], f1.z); atomicAdd(&acc1[d6], f1.w);
                atomicAdd(&acc2[d6], f2.x); atomicAdd(&acc3[d6], 1.0f);
            }
            if (d7 < BINSZ) {
                atomicAdd(&acc0[d7], f2.y); atomicAdd(&acc1[d7], f2.z);
                atomicAdd(&acc2[d7], f2.w); atomicAdd(&acc3[d7], 1.0f);
            }
        }
        ia = ian; ib = ibn;
        e8 = e8n;
    }
    __syncthreads();

    // writeback with SoA->AoS transpose (4 conflict-free b32 LDS reads/elem)
    {
        const int hi = min(BINSZ, N_NODES - lo);
        float* part_s = ws + PART_OFF;
        float* part_r = part_s + (size_t)nch * (N_NODES * 4);
        float* basep = (is_s ? part_s : part_r)
                     + (size_t)chunk * (N_NODES * 4) + (size_t)lo * 4;
        float4* dst = (float4*)basep;
        for (int i = tid; i < hi; i += BT)
            dst[i] = make_float4(acc0[i], acc1[i], acc2[i], acc3[i]);
    }
}

// ---- fallback path (tiny ws): global-atomic scatter into esr[node][8] ----
__global__ __launch_bounds__(256) void edge_kernel_atomic(
    const float* __restrict__ edges,
    const int*   __restrict__ senders,
    const int*   __restrict__ receivers,
    float* __restrict__ ws)
{
    const int e = blockIdx.x * 256 + threadIdx.x;
    if (e >= N_EDGES) return;
    const float e0 = edges[e * 3 + 0];
    const float e1 = edges[e * 3 + 1];
    const float e2 = edges[e * 3 + 2];
    const int s = senders[e];
    const int r = receivers[e];
    float* esr = ws + ESR_OFF;
    atomicAdd(&esr[s * 8 + 0], e0);
    atomicAdd(&esr[s * 8 + 1], e1);
    atomicAdd(&esr[s * 8 + 2], e2);
    atomicAdd(&esr[s * 8 + 3], 1.0f);
    atomicAdd(&esr[r * 8 + 4], e0);
    atomicAdd(&esr[r * 8 + 5], e1);
    atomicAdd(&esr[r * 8 + 6], e2);
    atomicAdd(&esr[r * 8 + 7], 1.0f);
}

// Node MLP, latency-split: 256 threads / 128 nodes per block (R6-proven).
__global__ __launch_bounds__(256) void node_kernel(
    const float* __restrict__ nodes,  // [N][16]
    const float* __restrict__ ws,
    const float* __restrict__ part_s,
    const float* __restrict__ part_r,
    float* __restrict__ out_nodes,    // d_out
    int nchunks)
{
    __shared__ float sh[2][128][8];
    __shared__ float red2[256];
    const int tid  = threadIdx.x;
    const int half = tid >> 7;          // 0/1, wave-uniform
    const int ln   = tid & 127;
    const int n    = blockIdx.x * 128 + ln;
    const bool valid = n < N_NODES;

    float4 n0 = make_float4(0,0,0,0), n1 = n0, n2 = n0, n3 = n0;
    if (valid) {
        const float4* np4 = (const float4*)(nodes + (size_t)n * 16);
        n0 = np4[0]; n1 = np4[1]; n2 = np4[2]; n3 = np4[3];
    }

    float4 es = make_float4(0.f, 0.f, 0.f, 0.f);
    float4 er = make_float4(0.f, 0.f, 0.f, 0.f);
    if (valid) {
        if (nchunks > 0) {
            for (int c = half; c < nchunks; c += 2) {
                const float4 a = *(const float4*)(part_s + (size_t)c * (N_NODES * 4) + (size_t)n * 4);
                const float4 b = *(const float4*)(part_r + (size_t)c * (N_NODES * 4) + (size_t)n * 4);
                es.x += a.x; es.y += a.y; es.z += a.z; es.w += a.w;
                er.x += b.x; er.y += b.y; er.z += b.z; er.w += b.w;
            }
        } else if (half == 0) {
            const float4* p = (const float4*)(ws + ESR_OFF + (size_t)n * 8);
            es = p[0];
            er = p[1];
        }
    }
    sh[half][ln][0] = es.x; sh[half][ln][1] = es.y;
    sh[half][ln][2] = es.z; sh[half][ln][3] = es.w;
    sh[half][ln][4] = er.x; sh[half][ln][5] = er.y;
    sh[half][ln][6] = er.z; sh[half][ln][7] = er.w;
    __syncthreads();
    es.x = sh[0][ln][0] + sh[1][ln][0];
    es.y = sh[0][ln][1] + sh[1][ln][1];
    es.z = sh[0][ln][2] + sh[1][ln][2];
    es.w = sh[0][ln][3] + sh[1][ln][3];
    er.x = sh[0][ln][4] + sh[1][ln][4];
    er.y = sh[0][ln][5] + sh[1][ln][5];
    er.z = sh[0][ln][6] + sh[1][ln][6];
    er.w = sh[0][ln][7] + sh[1][ln][7];

    const float* cst = ws + CONSTS_OFF + half * 64 * 32;  // this half's k-range
    float acc = 0.f;
#pragma unroll 4
    for (int kk = 0; kk < 64; ++kk) {
        const float4 m0 = *(const float4*)(cst + kk * 32 + 0);
        const float4 m1 = *(const float4*)(cst + kk * 32 + 4);
        const float4 m2 = *(const float4*)(cst + kk * 32 + 8);
        const float4 m3 = *(const float4*)(cst + kk * 32 + 12);
        const float4 q0 = *(const float4*)(cst + kk * 32 + 16);
        const float4 q1 = *(const float4*)(cst + kk * 32 + 20);
        const float4 q2 = *(const float4*)(cst + kk * 32 + 24);
        float pre = q1.z
            + n0.x * m0.x + n0.y * m0.y + n0.z * m0.z + n0.w * m0.w
            + n1.x * m1.x + n1.y * m1.y + n1.z * m1.z + n1.w * m1.w
            + n2.x * m2.x + n2.y * m2.y + n2.z * m2.z + n2.w * m2.w
            + n3.x * m3.x + n3.y * m3.y + n3.z * m3.z + n3.w * m3.w
            + es.x * q0.x + es.y * q0.y + es.z * q0.z
            + er.x * q0.w + er.y * q1.x + er.z * q1.y
            + es.w * q1.w + er.w * q2.x;
        acc += fmaxf(pre, 0.f) * q2.y;
    }
    red2[tid] = acc;
    __syncthreads();
    if (half == 0 && valid)
        out_nodes[n] = acc + red2[tid + 128] + (ws + CONSTS_OFF)[26];
}

extern "C" void kernel_launch(void* const* d_in, const int* in_sizes, int n_in,
                              void* d_out, int out_size, void* d_ws, size_t ws_size,
                              hipStream_t stream) {
    const float* nodes     = (const float*)d_in[0];
    const float* edges     = (const float*)d_in[1];
    const float* globals_  = (const float*)d_in[2];
    const int*   senders   = (const int*)d_in[3];
    const int*   receivers = (const int*)d_in[4];
    const float* W_en = (const float*)d_in[5];
    const float* b_en = (const float*)d_in[6];
    const float* W_ee = (const float*)d_in[7];
    const float* b_ee = (const float*)d_in[8];
    const float* W1   = (const float*)d_in[9];
    const float* b1   = (const float*)d_in[10];
    const float* W2   = (const float*)d_in[11];
    const float* b2   = (const float*)d_in[12];
    const float* W_dn = (const float*)d_in[13];
    const float* b_dn = (const float*)d_in[14];
    const float* W_de = (const float*)d_in[15];
    const float* b_de = (const float*)d_in[16];

    float* ws  = (float*)d_ws;
    float* out = (float*)d_out;
    float* out_edges = out + N_NODES;

    long ws_floats = (long)(ws_size / 4);
    long per_chunk = 2L * N_NODES * 4;
    long avail = (ws_floats - PART_OFF) / per_chunk;
    int nch = (int)(avail < 1 ? 0 : (avail > MAXCH ? MAXCH : avail));

    float* part_s = ws + PART_OFF;
    float* part_r = part_s + (size_t)(nch > 0 ? nch : 1) * (N_NODES * 4);

    int ce = (N_EDGES + (nch > 0 ? nch : 1) - 1) / (nch > 0 ? nch : 1);
    ce = (ce + 7) & ~7;   // keep 8-edge groups int4-aligned

    front_kernel<<<26 * (nch > 0 ? nch : 1), BT, 0, stream>>>(
        edges, globals_, senders, receivers,
        W_en, b_en, W_ee, b_ee, W1, b1, W2, b2,
        W_dn, b_dn, W_de, b_de, ws, out_edges, nch, ce);

    if (nch < 1) {
        hipMemsetAsync(ws + ESR_OFF, 0, (size_t)N_NODES * 8 * sizeof(float), stream);
        edge_kernel_atomic<<<(N_EDGES + 255) / 256, 256, 0, stream>>>(
            edges, senders, receivers, ws);
    }

    node_kernel<<<(N_NODES + 127) / 128, 256, 0, stream>>>(
        nodes, ws, part_s, part_r, out, nch);
}

// Round 12
// 154.284 us; speedup vs baseline: 1.3263x; 1.1377x over previous
//
#include <hip/hip_runtime.h>

#define N_NODES 50000
#define N_EDGES 800000

// ws layout (in floats):
//  [0, 400000)        esr[node][8] (fallback path only)
//  [400000, 404096)   consts[k][32]   (consts[26] = c_node bias)
//  [404608, ...)      part_s[c][node][4] then part_r[c][node][4]
#define ESR_OFF    0
#define CONSTS_OFF 400000
#define PART_OFF   404608

#define NBINS   13
#define BINSZ   4096     // 13*4096 = 53248 >= 50000; LDS 65536 B -> 2 blocks/CU
#define MAXCH   19       // 26*19 = 494 blocks, ~2 blocks/CU
#define BT      1024     // 16 waves/block (R6 config, byte-identical front)

// Fused front kernel — EXACT R6 configuration (50.7 us measured): AoS acc,
// BT=1024, launch_bounds(BT,8). Untouched this round (single-variable A/B:
// only node_kernel changes).
__global__ __launch_bounds__(BT, 8) void front_kernel(
    const float* __restrict__ edges,     // [E][3]
    const float* __restrict__ g,         // [8]
    const int*   __restrict__ senders,   // [E]
    const int*   __restrict__ receivers, // [E]
    const float* __restrict__ W_en, const float* __restrict__ b_en,
    const float* __restrict__ W_ee, const float* __restrict__ b_ee,
    const float* __restrict__ W1,   const float* __restrict__ b1,
    const float* __restrict__ W2,   const float* __restrict__ b2,
    const float* __restrict__ W_dn, const float* __restrict__ b_dn,
    const float* __restrict__ W_de, const float* __restrict__ b_de,
    float* __restrict__ ws,
    float* __restrict__ out_edges,       // [E]
    int nch, int ce)
{
    __shared__ float4 acc4[BINSZ];          // 65536 B; first 4 KB reused as red[]
    float* red = (float*)acc4;              // red[BT]
    float* acc = (float*)acc4;
    const int tid  = threadIdx.x;
    const int bid  = blockIdx.x;
    const int nblk = gridDim.x;

    // ---- per-block scalar constants ----
    if (tid < 512) {
        float v = 0.f;
        if (tid < 128)      v = b2[tid] * W_dn[tid];                    // -> c_node
        else if (tid < 256) v = b_ee[tid - 128] * W_de[tid - 128];      // -> cb
        else if (tid < 384) v = W_ee[tid - 256] * W_de[tid - 256];      // -> w0
        else                v = W_ee[128 + tid - 384] * W_de[tid - 384];// -> w1
        red[tid] = v;
    }
    __syncthreads();
    for (int w = 64; w > 0; w >>= 1) {
        if (tid < 512 && (tid & 127) < w) red[tid] += red[tid + w];
        __syncthreads();
    }
    const float c_node = red[0]   + b_dn[0];
    const float cb     = red[128] + b_de[0];
    const float w0     = red[256];
    const float w1     = red[384];
    __syncthreads();
    if (tid < 128) red[tid] = W_ee[256 + tid] * W_de[tid];
    __syncthreads();
    for (int w = 64; w > 0; w >>= 1) {
        if (tid < w) red[tid] += red[tid + w];
        __syncthreads();
    }
    const float w2 = red[0];
    __syncthreads();

    // ---- consts GEMV jobs: consts[k][s], s in [0,26) (blocks 0..25) ----
    const int k  = tid & 127;
    const int lh = tid >> 7;     // 0..7, wave-uniform
    float* consts = ws + CONSTS_OFF;
    for (int s = bid; s < 26; s += nblk) {
        if (s < 25) {
            const float* lhs; int off;
            if (s < 16)      { lhs = W_en + s * 128;        off = 0;   }
            else if (s < 19) { lhs = W_ee + (s - 16) * 128; off = 128; }
            else if (s < 22) { lhs = W_ee + (s - 19) * 128; off = 256; }
            else if (s == 22){ lhs = b_en;                  off = 0;   }
            else if (s == 23){ lhs = b_ee;                  off = 128; }
            else             { lhs = b_ee;                  off = 256; }
            float a = 0.f;
            const int l0 = lh * 16;
#pragma unroll
            for (int u = 0; u < 16; ++u)
                a += lhs[l0 + u] * W1[(off + l0 + u) * 128 + k];
            __syncthreads();
            red[tid] = a;
            __syncthreads();
            if (lh == 0) {
                float val = red[k] + red[k + 128] + red[k + 256] + red[k + 384]
                          + red[k + 512] + red[k + 640] + red[k + 768] + red[k + 896];
                if (s == 22) {
                    val += b1[k];
#pragma unroll
                    for (int j = 0; j < 8; ++j)
                        val += g[j] * W1[(384 + j) * 128 + k];
                }
                consts[k * 32 + s] = val;
            }
        } else {  // s == 25: consts[k][25] = W2[k][:] . W_dn; also c_node
            float a = 0.f;
            const int j0 = lh * 16;
#pragma unroll
            for (int u = 0; u < 16; ++u)
                a += W2[k * 128 + j0 + u] * W_dn[j0 + u];
            __syncthreads();
            red[tid] = a;
            __syncthreads();
            if (lh == 0) {
                consts[k * 32 + 25] = red[k] + red[k + 128] + red[k + 256] + red[k + 384]
                                    + red[k + 512] + red[k + 640] + red[k + 768] + red[k + 896];
                consts[k * 32 + 26] = c_node;   // node bias, read as cstl[26]
                consts[k * 32 + 27] = 0.f;
            }
        }
    }

    // ---- edge decoder output, grid-stride ----
    for (int q = bid * BT + tid; q < N_EDGES / 4; q += nblk * BT) {
        const int e4 = q * 4;
        const float4* ep = (const float4*)(edges + (size_t)e4 * 3);
        const float4 f0 = ep[0], f1 = ep[1], f2 = ep[2];
        float4 o;
        o.x = fmaf(f0.x, w0, fmaf(f0.y, w1, fmaf(f0.z, w2, cb)));
        o.y = fmaf(f0.w, w0, fmaf(f1.x, w1, fmaf(f1.y, w2, cb)));
        o.z = fmaf(f1.z, w0, fmaf(f1.w, w1, fmaf(f2.x, w2, cb)));
        o.w = fmaf(f2.y, w0, fmaf(f2.z, w1, fmaf(f2.w, w2, cb)));
        *(float4*)(out_edges + e4) = o;
    }

    if (nch <= 0) return;   // fallback path does aggregation elsewhere

    // ---- zero LDS accumulator ----
    __syncthreads();
    for (int i = tid; i < BINSZ; i += BT)
        acc4[i] = make_float4(0.f, 0.f, 0.f, 0.f);
    __syncthreads();

    // ---- binned aggregation (R6-proven loop) ----
    const int chunk = bid / 26;
    const int binid = bid % 26;
    const bool is_s = binid < NBINS;
    const int bin   = is_s ? binid : binid - NBINS;
    const int lo    = bin * BINSZ;
    const int* __restrict__ idx = is_s ? senders : receivers;

    const int e_beg = chunk * ce;
    const int e_end = min(e_beg + ce, N_EDGES);
    const int STRIDE = BT * 8;

    int e8 = e_beg + tid * 8;
    int4 ia = make_int4(-1, -1, -1, -1), ib = ia;
    if (e8 < e_end) {
        ia = *(const int4*)(idx + e8);
        ib = *(const int4*)(idx + e8 + 4);
    }
    while (e8 < e_end) {
        const int e8n = e8 + STRIDE;
        int4 ian = ia, ibn = ib;
        if (e8n < e_end) {                    // prefetch next iteration's indices
            ian = *(const int4*)(idx + e8n);
            ibn = *(const int4*)(idx + e8n + 4);
        }
        const unsigned d0 = (unsigned)(ia.x - lo), d1 = (unsigned)(ia.y - lo);
        const unsigned d2 = (unsigned)(ia.z - lo), d3 = (unsigned)(ia.w - lo);
        const unsigned d4 = (unsigned)(ib.x - lo), d5 = (unsigned)(ib.y - lo);
        const unsigned d6 = (unsigned)(ib.z - lo), d7 = (unsigned)(ib.w - lo);
        if ((d0 < BINSZ) | (d1 < BINSZ) | (d2 < BINSZ) | (d3 < BINSZ)) {
            const float4* ep = (const float4*)(edges + (size_t)e8 * 3);
            const float4 f0 = ep[0], f1 = ep[1], f2 = ep[2];
            if (d0 < BINSZ) {
                atomicAdd(&acc[d0 * 4 + 0], f0.x); atomicAdd(&acc[d0 * 4 + 1], f0.y);
                atomicAdd(&acc[d0 * 4 + 2], f0.z); atomicAdd(&acc[d0 * 4 + 3], 1.0f);
            }
            if (d1 < BINSZ) {
                atomicAdd(&acc[d1 * 4 + 0], f0.w); atomicAdd(&acc[d1 * 4 + 1], f1.x);
                atomicAdd(&acc[d1 * 4 + 2], f1.y); atomicAdd(&acc[d1 * 4 + 3], 1.0f);
            }
            if (d2 < BINSZ) {
                atomicAdd(&acc[d2 * 4 + 0], f1.z); atomicAdd(&acc[d2 * 4 + 1], f1.w);
                atomicAdd(&acc[d2 * 4 + 2], f2.x); atomicAdd(&acc[d2 * 4 + 3], 1.0f);
            }
            if (d3 < BINSZ) {
                atomicAdd(&acc[d3 * 4 + 0], f2.y); atomicAdd(&acc[d3 * 4 + 1], f2.z);
                atomicAdd(&acc[d3 * 4 + 2], f2.w); atomicAdd(&acc[d3 * 4 + 3], 1.0f);
            }
        }
        if ((d4 < BINSZ) | (d5 < BINSZ) | (d6 < BINSZ) | (d7 < BINSZ)) {
            const float4* ep = (const float4*)(edges + (size_t)e8 * 3 + 12);
            const float4 f0 = ep[0], f1 = ep[1], f2 = ep[2];
            if (d4 < BINSZ) {
                atomicAdd(&acc[d4 * 4 + 0], f0.x); atomicAdd(&acc[d4 * 4 + 1], f0.y);
                atomicAdd(&acc[d4 * 4 + 2], f0.z); atomicAdd(&acc[d4 * 4 + 3], 1.0f);
            }
            if (d5 < BINSZ) {
                atomicAdd(&acc[d5 * 4 + 0], f0.w); atomicAdd(&acc[d5 * 4 + 1], f1.x);
                atomicAdd(&acc[d5 * 4 + 2], f1.y); atomicAdd(&acc[d5 * 4 + 3], 1.0f);
            }
            if (d6 < BINSZ) {
                atomicAdd(&acc[d6 * 4 + 0], f1.z); atomicAdd(&acc[d6 * 4 + 1], f1.w);
                atomicAdd(&acc[d6 * 4 + 2], f2.x); atomicAdd(&acc[d6 * 4 + 3], 1.0f);
            }
            if (d7 < BINSZ) {
                atomicAdd(&acc[d7 * 4 + 0], f2.y); atomicAdd(&acc[d7 * 4 + 1], f2.z);
                atomicAdd(&acc[d7 * 4 + 2], f2.w); atomicAdd(&acc[d7 * 4 + 3], 1.0f);
            }
        }
        ia = ian; ib = ibn;
        e8 = e8n;
    }
    __syncthreads();

    // writeback (clamped: last bin overhangs N_NODES)
    {
        const int hi = min(BINSZ, N_NODES - lo);
        float* part_s = ws + PART_OFF;
        float* part_r = part_s + (size_t)nch * (N_NODES * 4);
        float* basep = (is_s ? part_s : part_r)
                     + (size_t)chunk * (N_NODES * 4) + (size_t)lo * 4;
        float4* dst = (float4*)basep;
        for (int i = tid; i < hi; i += BT)
            dst[i] = acc4[i];
    }
}

// ---- fallback path (tiny ws): global-atomic scatter into esr[node][8] ----
__global__ __launch_bounds__(256) void edge_kernel_atomic(
    const float* __restrict__ edges,
    const int*   __restrict__ senders,
    const int*   __restrict__ receivers,
    float* __restrict__ ws)
{
    const int e = blockIdx.x * 256 + threadIdx.x;
    if (e >= N_EDGES) return;
    const float e0 = edges[e * 3 + 0];
    const float e1 = edges[e * 3 + 1];
    const float e2 = edges[e * 3 + 2];
    const int s = senders[e];
    const int r = receivers[e];
    float* esr = ws + ESR_OFF;
    atomicAdd(&esr[s * 8 + 0], e0);
    atomicAdd(&esr[s * 8 + 1], e1);
    atomicAdd(&esr[s * 8 + 2], e2);
    atomicAdd(&esr[s * 8 + 3], 1.0f);
    atomicAdd(&esr[r * 8 + 4], e0);
    atomicAdd(&esr[r * 8 + 5], e1);
    atomicAdd(&esr[r * 8 + 6], e2);
    atomicAdd(&esr[r * 8 + 7], 1.0f);
}

// Node MLP, REBUILT (the R12 change). Hypothesis: the old node was ~40-47 us
// (hidden below the 48 us fills in every top-5): 1.5 waves/SIMD, 19-deep
// cross-XCD partial chain, 64-deep L2 s_load chain. Fixes:
//  - 512 threads / 128 nodes; quarter q = tid>>7.
//  - chunk-reduction split 4-way (<=5 chunk-pairs per quarter).
//  - consts staged ONCE into LDS (16 KB coalesced); k-loop reads are
//    wave-uniform LDS broadcasts (no per-iteration L2 latency).
//  - MLP k-loop split 4-way (32-deep); LDS combine, pad-9 (gcd(9,32)=1).
__global__ __launch_bounds__(512) void node_kernel(
    const float* __restrict__ nodes,  // [N][16]
    const float* __restrict__ ws,
    const float* __restrict__ part_s,
    const float* __restrict__ part_r,
    float* __restrict__ out_nodes,    // d_out
    int nchunks)
{
    __shared__ float cstl[4096];        // consts[k][32], 16 KB
    __shared__ float sh[4][128][9];     // es/er partials, padded (18.4 KB)
    __shared__ float red2[4][128];      // MLP partials (2 KB)
    const int tid = threadIdx.x;
    const int q   = tid >> 7;           // 0..3, wave-uniform
    const int ln  = tid & 127;
    const int n   = blockIdx.x * 128 + ln;
    const bool valid = n < N_NODES;

    // stage consts into LDS (coalesced, once)
    {
        float4* d4 = (float4*)cstl;
        const float4* s4 = (const float4*)(ws + CONSTS_OFF);
        for (int i = tid; i < 1024; i += 512)
            d4[i] = s4[i];
    }

    // phase 1: chunk reduction, quarter q handles c = q, q+4, ...
    float4 es = make_float4(0.f, 0.f, 0.f, 0.f);
    float4 er = make_float4(0.f, 0.f, 0.f, 0.f);
    if (valid) {
        if (nchunks > 0) {
            for (int c = q; c < nchunks; c += 4) {
                const float4 a = *(const float4*)(part_s + (size_t)c * (N_NODES * 4) + (size_t)n * 4);
                const float4 b = *(const float4*)(part_r + (size_t)c * (N_NODES * 4) + (size_t)n * 4);
                es.x += a.x; es.y += a.y; es.z += a.z; es.w += a.w;
                er.x += b.x; er.y += b.y; er.z += b.z; er.w += b.w;
            }
        } else if (q == 0) {
            const float4* p = (const float4*)(ws + ESR_OFF + (size_t)n * 8);
            es = p[0];
            er = p[1];
        }
    }
    sh[q][ln][0] = es.x; sh[q][ln][1] = es.y;
    sh[q][ln][2] = es.z; sh[q][ln][3] = es.w;
    sh[q][ln][4] = er.x; sh[q][ln][5] = er.y;
    sh[q][ln][6] = er.z; sh[q][ln][7] = er.w;
    __syncthreads();
    es.x = sh[0][ln][0] + sh[1][ln][0] + sh[2][ln][0] + sh[3][ln][0];
    es.y = sh[0][ln][1] + sh[1][ln][1] + sh[2][ln][1] + sh[3][ln][1];
    es.z = sh[0][ln][2] + sh[1][ln][2] + sh[2][ln][2] + sh[3][ln][2];
    es.w = sh[0][ln][3] + sh[1][ln][3] + sh[2][ln][3] + sh[3][ln][3];
    er.x = sh[0][ln][4] + sh[1][ln][4] + sh[2][ln][4] + sh[3][ln][4];
    er.y = sh[0][ln][5] + sh[1][ln][5] + sh[2][ln][5] + sh[3][ln][5];
    er.z = sh[0][ln][6] + sh[1][ln][6] + sh[2][ln][6] + sh[3][ln][6];
    er.w = sh[0][ln][7] + sh[1][ln][7] + sh[2][ln][7] + sh[3][ln][7];

    // node features (L2-resident; each quarter loads its own copy, coalesced)
    float4 n0 = make_float4(0,0,0,0), n1 = n0, n2 = n0, n3 = n0;
    if (valid) {
        const float4* np4 = (const float4*)(nodes + (size_t)n * 16);
        n0 = np4[0]; n1 = np4[1]; n2 = np4[2]; n3 = np4[3];
    }

    // phase 2: MLP over this quarter's k-range [q*32, q*32+32)
    const float* cst = cstl + q * 1024;   // (q*32)*32
    float acc = 0.f;
#pragma unroll 4
    for (int kk = 0; kk < 32; ++kk) {
        const float4 m0 = *(const float4*)(cst + kk * 32 + 0);
        const float4 m1 = *(const float4*)(cst + kk * 32 + 4);
        const float4 m2 = *(const float4*)(cst + kk * 32 + 8);
        const float4 m3 = *(const float4*)(cst + kk * 32 + 12);
        const float4 q0 = *(const float4*)(cst + kk * 32 + 16);
        const float4 q1 = *(const float4*)(cst + kk * 32 + 20);
        const float4 q2 = *(const float4*)(cst + kk * 32 + 24);
        float pre = q1.z
            + n0.x * m0.x + n0.y * m0.y + n0.z * m0.z + n0.w * m0.w
            + n1.x * m1.x + n1.y * m1.y + n1.z * m1.z + n1.w * m1.w
            + n2.x * m2.x + n2.y * m2.y + n2.z * m2.z + n2.w * m2.w
            + n3.x * m3.x + n3.y * m3.y + n3.z * m3.z + n3.w * m3.w
            + es.x * q0.x + es.y * q0.y + es.z * q0.z
            + er.x * q0.w + er.y * q1.x + er.z * q1.y
            + es.w * q1.w + er.w * q2.x;
        acc += fmaxf(pre, 0.f) * q2.y;
    }
    red2[q][ln] = acc;
    __syncthreads();
    if (q == 0 && valid)
        out_nodes[n] = red2[0][ln] + red2[1][ln] + red2[2][ln] + red2[3][ln]
                     + cstl[26];
}

extern "C" void kernel_launch(void* const* d_in, const int* in_sizes, int n_in,
                              void* d_out, int out_size, void* d_ws, size_t ws_size,
                              hipStream_t stream) {
    const float* nodes     = (const float*)d_in[0];
    const float* edges     = (const float*)d_in[1];
    const float* globals_  = (const float*)d_in[2];
    const int*   senders   = (const int*)d_in[3];
    const int*   receivers = (const int*)d_in[4];
    const float* W_en = (const float*)d_in[5];
    const float* b_en = (const float*)d_in[6];
    const float* W_ee = (const float*)d_in[7];
    const float* b_ee = (const float*)d_in[8];
    const float* W1   = (const float*)d_in[9];
    const float* b1   = (const float*)d_in[10];
    const float* W2   = (const float*)d_in[11];
    const float* b2   = (const float*)d_in[12];
    const float* W_dn = (const float*)d_in[13];
    const float* b_dn = (const float*)d_in[14];
    const float* W_de = (const float*)d_in[15];
    const float* b_de = (const float*)d_in[16];

    float* ws  = (float*)d_ws;
    float* out = (float*)d_out;
    float* out_edges = out + N_NODES;

    long ws_floats = (long)(ws_size / 4);
    long per_chunk = 2L * N_NODES * 4;
    long avail = (ws_floats - PART_OFF) / per_chunk;
    int nch = (int)(avail < 1 ? 0 : (avail > MAXCH ? MAXCH : avail));

    float* part_s = ws + PART_OFF;
    float* part_r = part_s + (size_t)(nch > 0 ? nch : 1) * (N_NODES * 4);

    int ce = (N_EDGES + (nch > 0 ? nch : 1) - 1) / (nch > 0 ? nch : 1);
    ce = (ce + 7) & ~7;   // keep 8-edge groups int4-aligned

    front_kernel<<<26 * (nch > 0 ? nch : 1), BT, 0, stream>>>(
        edges, globals_, senders, receivers,
        W_en, b_en, W_ee, b_ee, W1, b1, W2, b2,
        W_dn, b_dn, W_de, b_de, ws, out_edges, nch, ce);

    if (nch < 1) {
        hipMemsetAsync(ws + ESR_OFF, 0, (size_t)N_NODES * 8 * sizeof(float), stream);
        edge_kernel_atomic<<<(N_EDGES + 255) / 256, 256, 0, stream>>>(
            edges, senders, receivers, ws);
    }

    node_kernel<<<(N_NODES + 127) / 128, 512, 0, stream>>>(
        nodes, ws, part_s, part_r, out, nch);
}